// Round 9
// baseline (205.365 us; speedup 1.0000x reference)
//
#include <hip/hip_runtime.h>

// PathEmbedding fused kernel for MI355X (gfx950). Round 17.
//
// Math (exact restructure): att[p,l] = h_l . u_p, u_p = h15 @ Wqk,
// Wqk[k][i] = sum_v wq[k,v] wk[i,v]; context = (sum_l att_l h_l) @ wv.
//
// R17: MFMA operand-role swap in the GRU window. Compute D = W(A) x h(B):
// D[row=quad*4+r][col=c16] = [out-dim][path] -> each thread owns 4
// CONSECUTIVE dims of ONE path. Cuts per-window issue ~25%:
//   - 1 edge-id load (was 4); E-gather = 2x dwordx4 (was 4x8B + 4 addr chains)
//   - h-write = 2x v_cvt_pk_bf16_f32 + ds_write_b64 (was 8 ops + 4 ds_write_b16)
//   - z/r biases folded into E8 at eprep; persistent ZERO4/bhv as MFMA C-init
//     -> zero per-window accumulator-init movs.
// LDS arena stays [path][dim]: fragment b128 reads + epilogue E1-E5 are
// UNCHANGED (wpk packing formula is identical under the role swap).
// R16 lesson: lgkmcnt-only barrier ~neutral -> reverted to __syncthreads.
// R15 LESSON: reg file is at the 128-reg boundary; added pipeline state spills.
// R14 LESSON: waves_per_eu no-op; VGPR_Count excludes the AGPR side.
// R12 lesson: exp2-prescaled gates + MFMA-diag E3.
// R10 LESSON: rotation arrays -> SCRATCH; only NAMED vars via lambda args.
// R9 lesson: 2 WG/CU (LDS <= 80KB); R8: x-side precompute in E8.
// Fragment layouts (HW-verified): A[m=lane&15][k=quad*8+j],
// B[k=quad*8+j][n=lane&15], C/D[row=quad*4+reg][col=lane&15].

#define NUM_PATHS 30000
#define T 16
#define NTILES 1875
#define NEDGES 10000

#define SC1 1.4426950408889634f   // log2(e)
#define SC2 2.8853900817779268f   // 2*log2(e)

typedef float f32x4 __attribute__((ext_vector_type(4)));
typedef short bf16x8 __attribute__((ext_vector_type(8)));
typedef short bf16x4 __attribute__((ext_vector_type(4)));

// half-up rounding: max error 0.5 ulp, 2 VALU ops
__device__ __forceinline__ short f2bf(float f) {
    union { float f; unsigned u; } v; v.f = f;
    return (short)((v.u + 0x8000u) >> 16);
}
__device__ __forceinline__ float bf2f(short s) {
    union { unsigned u; float f; } v; v.u = ((unsigned)(unsigned short)s) << 16;
    return v.f;
}
// raw v_exp_f32 (2^x). neg variant uses the free VOP3 input modifier.
__device__ __forceinline__ float vexp2(float x) {
    float r; asm("v_exp_f32 %0, %1" : "=v"(r) : "v"(x)); return r;
}
__device__ __forceinline__ float vexp2n(float x) {
    float r; asm("v_exp_f32 %0, -%1" : "=v"(r) : "v"(x)); return r;
}
// packed f32->2xbf16 (RNE): dst.lo = bf16(a), dst.hi = bf16(b)
__device__ __forceinline__ unsigned cvtpk(float a, float b) {
    unsigned r; asm("v_cvt_pk_bf16_f32 %0, %1, %2" : "=v"(r) : "v"(a), "v"(b));
    return r;
}

#define MFMA(a, b, c) __builtin_amdgcn_mfma_f32_16x16x32_bf16((a), (b), (c), 0, 0, 0)

// ---------- prep: packed weight frags (formula identical under role swap) ----------
// wpk frag slot f, element ((f*8 + w)*64 + lane)*8 + j :
//   f 0..7  = Wz[kc] (k over [x;h])   f 8..15 = Wr[kc]      (scaled SC1)
//   f 16..19= Wxh[kc] (x side)        f 20..23 = Whh[kc]    (scaled SC2)
//   f 24..27= Wqk_hi[kc]              f 28..31 = Wqk_lo[kc]   (Wqk = wq.wk^T)
//   f 32..35= Wwv_hi[kc]              f 36..39 = Wwv_lo[kc]
#define GRU_T 12288
#define QK_T 16384
#define WV_T 2048
__global__ void prep_kernel(const float* __restrict__ Wx, const float* __restrict__ Wr,
                            const float* __restrict__ wq, const float* __restrict__ wk,
                            const float* __restrict__ wv,
                            short* __restrict__ wpk) {
    int id = blockIdx.x * 256 + threadIdx.x;
    if (id < GRU_T) {
        int f = id >> 9, rem = id & 511;
        int w = rem >> 6, lane = rem & 63;
        int quad = lane >> 4, c16 = lane & 15;
        int col = 16 * w + c16;
        short o[8];
        #pragma unroll
        for (int j = 0; j < 8; ++j) {
            float v;
            if (f < 16) {
                int k = (f & 7) * 32 + quad * 8 + j;          // 0..255 over [x;h]
                int cc = col + ((f < 8) ? 0 : 128);
                v = ((k < 128) ? Wx[k * 384 + cc] : Wr[(k - 128) * 384 + cc]) * SC1;
            } else {
                int k = ((f - 16) & 3) * 32 + quad * 8 + j;   // 0..127
                v = ((f < 20) ? Wx[k * 384 + 256 + col] : Wr[k * 384 + 256 + col]) * SC2;
            }
            o[j] = f2bf(v);
        }
        *(bf16x8*)&wpk[id * 8] = *(bf16x8*)o;
        return;
    }
    if (id < GRU_T + QK_T) {
        int t2 = id - GRU_T;
        int j = t2 & 7, lane = (t2 >> 3) & 63, w = (t2 >> 9) & 7, kc = t2 >> 12;
        int quad = lane >> 4, c16 = lane & 15, col = 16 * w + c16;
        int k = kc * 32 + quad * 8 + j;
        const float* qr = wq + k * 128;
        const float* kr = wk + col * 128;
        float s = 0.f;
        #pragma unroll 8
        for (int vv = 0; vv < 128; ++vv) s += qr[vv] * kr[vv];
        short hi = f2bf(s);
        wpk[(((24 + kc) * 8 + w) * 64 + lane) * 8 + j] = hi;
        wpk[(((28 + kc) * 8 + w) * 64 + lane) * 8 + j] = f2bf(s - bf2f(hi));
        return;
    }
    if (id < GRU_T + QK_T + WV_T) {
        int t2 = id - GRU_T - QK_T;
        int lane = t2 & 63, w = (t2 >> 6) & 7, kc = t2 >> 9;
        int quad = lane >> 4, c16 = lane & 15, col = 16 * w + c16;
        short hi8[8], lo8[8];
        #pragma unroll
        for (int j = 0; j < 8; ++j) {
            float v = wv[(kc * 32 + quad * 8 + j) * 128 + col];
            hi8[j] = f2bf(v);
            lo8[j] = f2bf(v - bf2f(hi8[j]));
        }
        *(bf16x8*)&wpk[(((32 + kc) * 8 + w) * 64 + lane) * 8] = *(bf16x8*)hi8;
        *(bf16x8*)&wpk[(((36 + kc) * 8 + w) * 64 + lane) * 8] = *(bf16x8*)lo8;
    }
}

// ---------- eprep: E8[e*128 + d] = {pack(zpre+bz', rpre+br') bf16x2, xh'+bxh' f32} --
// z/r combined biases now folded here (R17); bxh as before. All pre-scaled.
__global__ __launch_bounds__(512) void eprep_kernel(
    const float* __restrict__ inputs, const short* __restrict__ wpk,
    const float* __restrict__ bias_i, const float* __restrict__ bias_r,
    uint2* __restrict__ E8) {
    const int w = threadIdx.x >> 6, lane = threadIdx.x & 63;
    const int quad = lane >> 4, c16 = lane & 15;
    const int ucol = 16 * w + c16;
    const int e0 = blockIdx.x * 16;

    const float bxh = bias_i[256 + ucol] * SC2;
    const float bzc = (bias_i[ucol] + bias_r[ucol]) * SC1;
    const float brc = (bias_i[128 + ucol] + bias_r[128 + ucol]) * SC1;

    bf16x8 A[4];
    const float* row = inputs + (e0 + c16) * 128;
    #pragma unroll
    for (int kc = 0; kc < 4; ++kc) {
        float4 a = *(const float4*)&row[kc * 32 + quad * 8];
        float4 b = *(const float4*)&row[kc * 32 + quad * 8 + 4];
        short o[8] = {f2bf(a.x), f2bf(a.y), f2bf(a.z), f2bf(a.w),
                      f2bf(b.x), f2bf(b.y), f2bf(b.z), f2bf(b.w)};
        A[kc] = *(bf16x8*)o;
    }
    f32x4 az = {0.f, 0.f, 0.f, 0.f}, ar = az, ax = az;
    #pragma unroll
    for (int kc = 0; kc < 4; ++kc) {
        bf16x8 Bz = *(const bf16x8*)&wpk[(((0 + kc) * 8 + w) * 64 + lane) * 8];
        bf16x8 Br = *(const bf16x8*)&wpk[(((8 + kc) * 8 + w) * 64 + lane) * 8];
        bf16x8 Bx = *(const bf16x8*)&wpk[(((16 + kc) * 8 + w) * 64 + lane) * 8];
        az = MFMA(A[kc], Bz, az);
        ar = MFMA(A[kc], Br, ar);
        ax = MFMA(A[kc], Bx, ax);
    }
    #pragma unroll
    for (int r = 0; r < 4; ++r) {
        unsigned zr = (unsigned)(unsigned short)f2bf(az[r] + bzc) |
                      ((unsigned)(unsigned short)f2bf(ar[r] + brc) << 16);
        uint2 val;
        val.x = zr;
        val.y = __float_as_uint(ax[r] + bxh);
        E8[(e0 + quad * 4 + r) * 128 + ucol] = val;
    }
}

#define ROWS 136    // padded row stride (shorts): <=2-way LDS conflicts on b128 reads
#define HSLOT 2184  // 16*136+8: +4-word slot rotation

__global__ __launch_bounds__(512, 4) void path_emb_kernel(
    const int* __restrict__ paths, const short* __restrict__ wpk,
    const uint2* __restrict__ E8,
    const float* __restrict__ bias_i, const float* __restrict__ bias_r,
    float* __restrict__ out)
{
    __shared__ __align__(16) short s_hist[16][HSLOT]; // h history [path][dim] (69,888 B)
    __shared__ __align__(16) short s_xb[2][T * ROWS]; // epilogue bufs        (8,704 B)
    __shared__ float s_att[16][20];                   // att                  (1,280 B)
    // total 79,872 B -> 2 WG/CU

    const int tid  = threadIdx.x;
    const int w    = tid >> 6;
    const int lane = tid & 63;
    const int quad = lane >> 4;
    const int c16  = lane & 15;
    const int ucol = 16 * w + c16;
    const int d0   = 16 * w + quad * 4;   // this thread's 4 consecutive dims

    // persistent weight A-frags (same wpk slots; role-swapped semantics)
    bf16x8 Azh[4], Arh[4], Ahh[4];
    #pragma unroll
    for (int kc = 0; kc < 4; ++kc) {
        Azh[kc] = *(const bf16x8*)&wpk[(((4 + kc)  * 8 + w) * 64 + lane) * 8];
        Arh[kc] = *(const bf16x8*)&wpk[(((12 + kc) * 8 + w) * 64 + lane) * 8];
        Ahh[kc] = *(const bf16x8*)&wpk[(((20 + kc) * 8 + w) * 64 + lane) * 8];
    }

    // persistent C-init vectors: zero for z/r (bias folded into E8), bhh for cand
    f32x4 bhv;
    {
        float4 b4 = *(const float4*)&bias_r[256 + d0];
        bhv[0] = b4.x * SC2; bhv[1] = b4.y * SC2;
        bhv[2] = b4.z * SC2; bhv[3] = b4.w * SC2;
    }
    f32x4 ZV = {0.f, 0.f, 0.f, 0.f};

    const int p0 = blockIdx.x * T;

    float hA[4] = {0.f, 0.f, 0.f, 0.f};  // h[path=c16][d0+r]

    // per-thread path row of ids; per-thread E base at its 4 dims
    const int* pb = paths + (p0 + c16) * 16;
    const uint2* Ebase = E8 + d0;

    // ---- 2-deep pipeline: NAMED uint4 pairs rotated via lambda args ----
    uint4 Ea0, Ea1, Eb0, Eb1, Ec0, Ec1;
    {
        int i0 = pb[0], i1 = pb[1];
        const uint4* e0p = (const uint4*)(Ebase + (size_t)i0 * 128);
        const uint4* e1p = (const uint4*)(Ebase + (size_t)i1 * 128);
        Ea0 = e0p[0]; Ea1 = e0p[1];
        Eb0 = e1p[0]; Eb1 = e1p[1];
    }

    // gate: ZR = packed(z-preact+bias, r-preact+bias) bf16x2, XH = xh f32
    #define GATE(r, ZR, XH) {                                                  \
        float zx = __uint_as_float((ZR) << 16);                                \
        float rx = __uint_as_float((ZR) & 0xffff0000u);                        \
        float xh = __uint_as_float(XH);                                        \
        float z    = __builtin_amdgcn_rcpf(1.0f + vexp2n(az[r] + zx));         \
        float rr   = __builtin_amdgcn_rcpf(1.0f + vexp2n(ar[r] + rx));         \
        float e2   = vexp2(xh + rr * ach[r]);                                  \
        float cand = 1.0f - 2.0f * __builtin_amdgcn_rcpf(1.0f + e2);           \
        hA[r] = cand + z * (hA[r] - cand); }

    // window t: consume E(t) from (c0,c1); gather E(t+2) into (n0,n1).
    auto window = [&](int t, uint4& c0, uint4& c1, uint4& n0, uint4& n1) {
        __syncthreads();  // h_{t-1} writes (all waves) visible

        if (t < 14) {
            int en = pb[t + 2];
            const uint4* ep = (const uint4*)(Ebase + (size_t)en * 128);
            n0 = ep[0]; n1 = ep[1];
        }

        f32x4 az = ZV, ar = ZV, ach = bhv;

        if (t > 0) {
            bf16x8 bh[4];
            #pragma unroll
            for (int kc = 0; kc < 4; ++kc)
                bh[kc] = *(const bf16x8*)&s_hist[t - 1][c16 * ROWS + kc * 32 + quad * 8];
            __builtin_amdgcn_s_setprio(1);
            #pragma unroll
            for (int kc = 0; kc < 4; ++kc) {
                az  = MFMA(Azh[kc], bh[kc], az);
                ar  = MFMA(Arh[kc], bh[kc], ar);
                ach = MFMA(Ahh[kc], bh[kc], ach);
            }
            __builtin_amdgcn_s_setprio(0);
        }

        GATE(0, c0.x, c0.y)
        GATE(1, c0.z, c0.w)
        GATE(2, c1.x, c1.y)
        GATE(3, c1.z, c1.w)

        // 4 consecutive dims of one path: packed bf16 write, one ds_write_b64
        uint2 pk;
        pk.x = cvtpk(hA[0], hA[1]);
        pk.y = cvtpk(hA[2], hA[3]);
        *(uint2*)&s_hist[t][c16 * ROWS + d0] = pk;
    };

    // consume cycle A,B,C; prefetch target = consume buffer of t+2
    #pragma unroll 1
    for (int t3 = 0; t3 < 5; ++t3) {
        window(3 * t3 + 0, Ea0, Ea1, Ec0, Ec1);
        window(3 * t3 + 1, Eb0, Eb1, Ea0, Ea1);
        window(3 * t3 + 2, Ec0, Ec1, Eb0, Eb1);
    }
    window(15, Ea0, Ea1, Ec0, Ec1);

    // ---------------- epilogue (one tile) ----------------
    // E0: h15 lo residual -> xb[0] (packed; must match hist's RNE rounding)
    {
        unsigned q0 = cvtpk(hA[0], hA[1]);
        unsigned q1 = cvtpk(hA[2], hA[3]);
        float l0 = hA[0] - bf2f((short)(q0 & 0xffffu));
        float l1 = hA[1] - bf2f((short)(q0 >> 16));
        float l2 = hA[2] - bf2f((short)(q1 & 0xffffu));
        float l3 = hA[3] - bf2f((short)(q1 >> 16));
        uint2 rk;
        rk.x = cvtpk(l0, l1);
        rk.y = cvtpk(l2, l3);
        *(uint2*)&s_xb[0][c16 * ROWS + d0] = rk;
    }
    __syncthreads();  // b1: hist[15] + residuals visible

    // E1: u = h15 @ Wqk (hi/lo split, 12 MFMAs)  [unchanged]
    f32x4 uA = {0.f, 0.f, 0.f, 0.f};
    #pragma unroll
    for (int kc = 0; kc < 4; ++kc) {
        bf16x8 bqh = *(const bf16x8*)&wpk[(((24 + kc) * 8 + w) * 64 + lane) * 8];
        bf16x8 bql = *(const bf16x8*)&wpk[(((28 + kc) * 8 + w) * 64 + lane) * 8];
        bf16x8 Ah  = *(const bf16x8*)&s_hist[15][c16 * ROWS + kc * 32 + quad * 8];
        bf16x8 Al  = *(const bf16x8*)&s_xb[0][c16 * ROWS + kc * 32 + quad * 8];
        uA = MFMA(Ah, bqh, uA); uA = MFMA(Ah, bql, uA); uA = MFMA(Al, bqh, uA);
    }
    __syncthreads();  // b2: E1's xb reads done

    // E2: u hi/lo (C-scatter)  [unchanged: D here is [path][u-dim]]
    #pragma unroll
    for (int r = 0; r < 4; ++r) {
        int off = (quad * 4 + r) * ROWS + ucol;
        float v = uA[r]; short hi = f2bf(v);
        s_xb[0][off] = hi; s_xb[1][off] = f2bf(v - bf2f(hi));
    }
    __syncthreads();  // b3

    // E3: att[p][l] = diag(U @ H_l^T) via MFMA; wave w does l = 2w, 2w+1.  [unchanged]
    {
        bf16x8 Uh[4], Ul[4];
        #pragma unroll
        for (int kc = 0; kc < 4; ++kc) {
            Uh[kc] = *(const bf16x8*)&s_xb[0][c16 * ROWS + kc * 32 + quad * 8];
            Ul[kc] = *(const bf16x8*)&s_xb[1][c16 * ROWS + kc * 32 + quad * 8];
        }
        #pragma unroll
        for (int li = 0; li < 2; ++li) {
            int l = 2 * w + li;
            f32x4 acc = {0.f, 0.f, 0.f, 0.f};
            #pragma unroll
            for (int kc = 0; kc < 4; ++kc) {
                bf16x8 Bh = *(const bf16x8*)&s_hist[l][c16 * ROWS + kc * 32 + quad * 8];
                acc = MFMA(Uh[kc], Bh, acc);
                acc = MFMA(Ul[kc], Bh, acc);
            }
            float d01 = (c16 & 1) ? acc[1] : acc[0];
            float d23 = (c16 & 1) ? acc[3] : acc[2];
            float dv  = (c16 & 2) ? d23 : d01;
            if (quad == (c16 >> 2)) s_att[c16][l] = dv;
        }
    }
    __syncthreads();  // b4

    // E4: ctx[p][v] = sum_l att[p][l] * hist_l[p][v]; hi/lo split  [unchanged]
    {
        int p = tid >> 5, c0 = (tid & 31) * 4;
        float ctx[4] = {0.f, 0.f, 0.f, 0.f};
        #pragma unroll
        for (int l = 0; l < 16; ++l) {
            float al = s_att[p][l];
            bf16x4 hv = *(const bf16x4*)&s_hist[l][p * ROWS + c0];
            #pragma unroll
            for (int j = 0; j < 4; ++j) ctx[j] += al * bf2f(hv[j]);
        }
        #pragma unroll
        for (int j = 0; j < 4; ++j) {
            short hi = f2bf(ctx[j]);
            s_xb[0][p * ROWS + c0 + j] = hi;
            s_xb[1][p * ROWS + c0 + j] = f2bf(ctx[j] - bf2f(hi));
        }
    }
    __syncthreads();  // b5

    // E5: out = ctx @ wv (hi/lo split)  [unchanged]
    f32x4 oA = {0.f, 0.f, 0.f, 0.f};
    #pragma unroll
    for (int kc = 0; kc < 4; ++kc) {
        bf16x8 bwh = *(const bf16x8*)&wpk[(((32 + kc) * 8 + w) * 64 + lane) * 8];
        bf16x8 bwl = *(const bf16x8*)&wpk[(((36 + kc) * 8 + w) * 64 + lane) * 8];
        bf16x8 Ah  = *(const bf16x8*)&s_xb[0][c16 * ROWS + kc * 32 + quad * 8];
        bf16x8 Al  = *(const bf16x8*)&s_xb[1][c16 * ROWS + kc * 32 + quad * 8];
        oA = MFMA(Ah, bwh, oA); oA = MFMA(Ah, bwl, oA); oA = MFMA(Al, bwh, oA);
    }
    #pragma unroll
    for (int r = 0; r < 4; ++r)
        out[(p0 + quad * 4 + r) * 128 + ucol] = oA[r];
}

extern "C" void kernel_launch(void* const* d_in, const int* in_sizes, int n_in,
                              void* d_out, int out_size, void* d_ws, size_t ws_size,
                              hipStream_t stream) {
    const float* inputs = (const float*)d_in[0];
    const int*   paths  = (const int*)d_in[1];
    // d_in[2]=idx, d_in[3]=seqs: layout known (p*16+s), unused
    const float* wx  = (const float*)d_in[4];
    const float* wr  = (const float*)d_in[5];
    const float* bi  = (const float*)d_in[6];
    const float* br  = (const float*)d_in[7];
    const float* wq  = (const float*)d_in[8];
    const float* wk  = (const float*)d_in[9];
    const float* wvp = (const float*)d_in[10];

    // workspace: E8 10,240,000 B | wpk 327,680 B  (total ~10.6 MB)
    char* ws = (char*)d_ws;
    uint2* E8 = (uint2*)ws;
    short* wpk = (short*)(ws + 10240000);

    int prep_n = GRU_T + QK_T + WV_T;
    prep_kernel<<<(prep_n + 255) / 256, 256, 0, stream>>>(wx, wr, wq, wk, wvp, wpk);
    eprep_kernel<<<NEDGES / 16, 512, 0, stream>>>(inputs, wpk, bi, br, E8);
    path_emb_kernel<<<NTILES, 512, 0, stream>>>(paths, wpk, E8, bi, br, (float*)d_out);
}

// Round 10
// 195.513 us; speedup vs baseline: 1.0504x; 1.0504x over previous
//
#include <hip/hip_runtime.h>

// PathEmbedding fused kernel for MI355X (gfx950). Round 18.
//
// Math (exact restructure): att[p,l] = h_l . u_p, u_p = h15 @ Wqk,
// Wqk[k][i] = sum_v wq[k,v] wk[i,v]; context = (sum_l att_l h_l) @ wv.
//
// R18: revert to verified-best body (R12/R14, 111-112us x3 measurements),
// minus s_setprio (m190: setprio is ~0/negative on barrier-locked lockstep
// wave groups; our window loop is GEMM-like lockstep, and prio-boosting one
// block's MFMA burst can starve the co-resident block's gate VALU).
// R17 LESSON: operand-role swap cut VALU issue 52->41% but LOST 12% --
// the kernel is at a multi-resource balance point; the window wall is a
// blend of LDS read-amplification (each wave reads full h[t-1] as its MFMA
// A-operand: 32KB/window/block, algorithmically minimal for 8-wave split),
// MFMA chains, gate chains, and barrier convoy. No single pipe >60%.
// R16 lesson: lgkmcnt-only barrier neutral; vmcnt-drain theory dead.
// R15 LESSON: reg file is at the 128-reg boundary (64 VGPR + ~64 AGPR);
// ANY added pipeline state spills (WRITE 26->196MB tripwire).
// R14 LESSON: waves_per_eu no-op; VGPR_Count excludes the AGPR side.
// R12 lesson: exp2-prescaled gates + MFMA-diag E3 cut VALU 60->51%.
// R10 LESSON: rotation arrays (buf[t%N]) -> SCRATCH (SROA before unroll);
// only distinct NAMED arrays passed as lambda args are promoted.
// R9 lesson: 2 WG/CU (LDS <= 80KB) absorbs part of barrier stall.
// R8 lesson: x-side precompute (E8 per-edge preacts).
// Fragment layouts (HW-verified): A[m=lane&15][k=quad*8+j],
// B[k=quad*8+j][n=lane&15], C/D[row=quad*4+reg][col=lane&15].

#define NUM_PATHS 30000
#define T 16
#define NTILES 1875
#define NEDGES 10000

#define SC1 1.4426950408889634f   // log2(e)
#define SC2 2.8853900817779268f   // 2*log2(e)

typedef float f32x4 __attribute__((ext_vector_type(4)));
typedef short bf16x8 __attribute__((ext_vector_type(8)));
typedef short bf16x4 __attribute__((ext_vector_type(4)));

// half-up rounding: max error 0.5 ulp, 2 VALU ops
__device__ __forceinline__ short f2bf(float f) {
    union { float f; unsigned u; } v; v.f = f;
    return (short)((v.u + 0x8000u) >> 16);
}
__device__ __forceinline__ float bf2f(short s) {
    union { unsigned u; float f; } v; v.u = ((unsigned)(unsigned short)s) << 16;
    return v.f;
}
// raw v_exp_f32 (2^x). neg variant uses the free VOP3 input modifier.
__device__ __forceinline__ float vexp2(float x) {
    float r; asm("v_exp_f32 %0, %1" : "=v"(r) : "v"(x)); return r;
}
__device__ __forceinline__ float vexp2n(float x) {
    float r; asm("v_exp_f32 %0, -%1" : "=v"(r) : "v"(x)); return r;
}

#define MFMA(a, b, c) __builtin_amdgcn_mfma_f32_16x16x32_bf16((a), (b), (c), 0, 0, 0)

// ---------- prep: packed B-frags only ----------
// wpk frag slot f, element ((f*8 + w)*64 + lane)*8 + j :
//   f 0..7  = Bz[kc] (k over [x;h])   f 8..15 = Br[kc]      (scaled SC1)
//   f 16..19= Bxh[kc] (x side)        f 20..23 = Bhh[kc]    (scaled SC2)
//   f 24..27= Bqk_hi[kc]              f 28..31 = Bqk_lo[kc]   (Wqk = wq.wk^T)
//   f 32..35= Bwv_hi[kc]              f 36..39 = Bwv_lo[kc]
#define GRU_T 12288
#define QK_T 16384
#define WV_T 2048
__global__ void prep_kernel(const float* __restrict__ Wx, const float* __restrict__ Wr,
                            const float* __restrict__ wq, const float* __restrict__ wk,
                            const float* __restrict__ wv,
                            short* __restrict__ wpk) {
    int id = blockIdx.x * 256 + threadIdx.x;
    if (id < GRU_T) {
        int f = id >> 9, rem = id & 511;
        int w = rem >> 6, lane = rem & 63;
        int quad = lane >> 4, c16 = lane & 15;
        int col = 16 * w + c16;
        short o[8];
        #pragma unroll
        for (int j = 0; j < 8; ++j) {
            float v;
            if (f < 16) {
                int k = (f & 7) * 32 + quad * 8 + j;          // 0..255 over [x;h]
                int cc = col + ((f < 8) ? 0 : 128);
                v = ((k < 128) ? Wx[k * 384 + cc] : Wr[(k - 128) * 384 + cc]) * SC1;
            } else {
                int k = ((f - 16) & 3) * 32 + quad * 8 + j;   // 0..127
                v = ((f < 20) ? Wx[k * 384 + 256 + col] : Wr[k * 384 + 256 + col]) * SC2;
            }
            o[j] = f2bf(v);
        }
        *(bf16x8*)&wpk[id * 8] = *(bf16x8*)o;
        return;
    }
    if (id < GRU_T + QK_T) {
        int t2 = id - GRU_T;
        int j = t2 & 7, lane = (t2 >> 3) & 63, w = (t2 >> 9) & 7, kc = t2 >> 12;
        int quad = lane >> 4, c16 = lane & 15, col = 16 * w + c16;
        int k = kc * 32 + quad * 8 + j;
        const float* qr = wq + k * 128;
        const float* kr = wk + col * 128;
        float s = 0.f;
        #pragma unroll 8
        for (int vv = 0; vv < 128; ++vv) s += qr[vv] * kr[vv];
        short hi = f2bf(s);
        wpk[(((24 + kc) * 8 + w) * 64 + lane) * 8 + j] = hi;
        wpk[(((28 + kc) * 8 + w) * 64 + lane) * 8 + j] = f2bf(s - bf2f(hi));
        return;
    }
    if (id < GRU_T + QK_T + WV_T) {
        int t2 = id - GRU_T - QK_T;
        int lane = t2 & 63, w = (t2 >> 6) & 7, kc = t2 >> 9;
        int quad = lane >> 4, c16 = lane & 15, col = 16 * w + c16;
        short hi8[8], lo8[8];
        #pragma unroll
        for (int j = 0; j < 8; ++j) {
            float v = wv[(kc * 32 + quad * 8 + j) * 128 + col];
            hi8[j] = f2bf(v);
            lo8[j] = f2bf(v - bf2f(hi8[j]));
        }
        *(bf16x8*)&wpk[(((32 + kc) * 8 + w) * 64 + lane) * 8] = *(bf16x8*)hi8;
        *(bf16x8*)&wpk[(((36 + kc) * 8 + w) * 64 + lane) * 8] = *(bf16x8*)lo8;
    }
}

// ---------- eprep: E8[e*128 + ucol] = {pack(z,r) bf16x2, xh'+bxh' f32} ----------
// Preacts come out pre-scaled (weights scaled in prep); bxh scaled here.
__global__ __launch_bounds__(512) void eprep_kernel(
    const float* __restrict__ inputs, const short* __restrict__ wpk,
    const float* __restrict__ bias_i, uint2* __restrict__ E8) {
    const int w = threadIdx.x >> 6, lane = threadIdx.x & 63;
    const int quad = lane >> 4, c16 = lane & 15;
    const int ucol = 16 * w + c16;
    const int e0 = blockIdx.x * 16;

    const float bxh = bias_i[256 + ucol] * SC2;

    bf16x8 A[4];
    const float* row = inputs + (e0 + c16) * 128;
    #pragma unroll
    for (int kc = 0; kc < 4; ++kc) {
        float4 a = *(const float4*)&row[kc * 32 + quad * 8];
        float4 b = *(const float4*)&row[kc * 32 + quad * 8 + 4];
        short o[8] = {f2bf(a.x), f2bf(a.y), f2bf(a.z), f2bf(a.w),
                      f2bf(b.x), f2bf(b.y), f2bf(b.z), f2bf(b.w)};
        A[kc] = *(bf16x8*)o;
    }
    f32x4 az = {0.f, 0.f, 0.f, 0.f}, ar = az, ax = az;
    #pragma unroll
    for (int kc = 0; kc < 4; ++kc) {
        bf16x8 Bz = *(const bf16x8*)&wpk[(((0 + kc) * 8 + w) * 64 + lane) * 8];
        bf16x8 Br = *(const bf16x8*)&wpk[(((8 + kc) * 8 + w) * 64 + lane) * 8];
        bf16x8 Bx = *(const bf16x8*)&wpk[(((16 + kc) * 8 + w) * 64 + lane) * 8];
        az = MFMA(A[kc], Bz, az);
        ar = MFMA(A[kc], Br, ar);
        ax = MFMA(A[kc], Bx, ax);
    }
    #pragma unroll
    for (int r = 0; r < 4; ++r) {
        unsigned zr = (unsigned)(unsigned short)f2bf(az[r]) |
                      ((unsigned)(unsigned short)f2bf(ar[r]) << 16);
        uint2 val;
        val.x = zr;
        val.y = __float_as_uint(ax[r] + bxh);
        E8[(e0 + quad * 4 + r) * 128 + ucol] = val;
    }
}

#define ROWS 136    // padded row stride (shorts): <=2-way LDS conflicts
#define HSLOT 2184  // 16*136+8: +4-word slot rotation

__global__ __launch_bounds__(512, 4) void path_emb_kernel(
    const int* __restrict__ paths, const short* __restrict__ wpk,
    const uint2* __restrict__ E8,
    const float* __restrict__ bias_i, const float* __restrict__ bias_r,
    float* __restrict__ out)
{
    __shared__ __align__(16) short s_hist[16][HSLOT]; // h history, one tile (69,888 B)
    __shared__ __align__(16) short s_xb[2][T * ROWS]; // epilogue bufs       (8,704 B)
    __shared__ float s_att[16][20];                   // att                 (1,280 B)
    // total 79,872 B -> 2 WG/CU (16 waves/CU = 4 waves/EU)

    const int tid  = threadIdx.x;
    const int w    = tid >> 6;
    const int lane = tid & 63;
    const int quad = lane >> 4;
    const int c16  = lane & 15;
    const int ucol = 16 * w + c16;

    const float bz  = (bias_i[ucol] + bias_r[ucol]) * SC1;
    const float brr = (bias_i[128 + ucol] + bias_r[128 + ucol]) * SC1;
    const float bhh = bias_r[256 + ucol] * SC2;

    // persistent h-side GRU B-frags (live in AGPRs; R15 lesson)
    bf16x8 Bzh[4], Brh[4], Bhh[4];
    #pragma unroll
    for (int kc = 0; kc < 4; ++kc) {
        Bzh[kc] = *(const bf16x8*)&wpk[(((4 + kc)  * 8 + w) * 64 + lane) * 8];
        Brh[kc] = *(const bf16x8*)&wpk[(((12 + kc) * 8 + w) * 64 + lane) * 8];
        Bhh[kc] = *(const bf16x8*)&wpk[(((20 + kc) * 8 + w) * 64 + lane) * 8];
    }

    const int p0 = blockIdx.x * T;

    float hA[4] = {0.f, 0.f, 0.f, 0.f};

    // one base pointer for this thread's 4 path rows; all loads base+imm
    const int* pbase = paths + (p0 + quad * 4) * 16;
    const uint2* Erow = E8 + ucol;

    // ---- 2-deep pipeline: three NAMED buffers, rotated via lambda args ----
    uint2 Ea[4], Eb[4], Ec[4];

    { // prologue: E(0)->Ea, E(1)->Eb
        int id0[4], id1[4];
        #pragma unroll
        for (int i = 0; i < 4; ++i) id0[i] = pbase[i * 16 + 0];
        #pragma unroll
        for (int i = 0; i < 4; ++i) id1[i] = pbase[i * 16 + 1];
        #pragma unroll
        for (int i = 0; i < 4; ++i) Ea[i] = Erow[id0[i] * 128];
        #pragma unroll
        for (int i = 0; i < 4; ++i) Eb[i] = Erow[id1[i] * 128];
    }

    // window t: consume Ecur=E(t); issue id(t+2)->E(t+2) chain into Enxt.
    auto window = [&](int t, uint2* Ecur, uint2* Enxt) {
        __syncthreads();  // h_{t-1} writes (all waves) visible

        if (t < 14) {
            int en[4];
            #pragma unroll
            for (int i = 0; i < 4; ++i)
                en[i] = pbase[i * 16 + t + 2];
            #pragma unroll
            for (int i = 0; i < 4; ++i) Enxt[i] = Erow[en[i] * 128];
        }

        f32x4 az  = {bz, bz, bz, bz};
        f32x4 ar  = {brr, brr, brr, brr};
        f32x4 ach = {bhh, bhh, bhh, bhh};

        if (t > 0) {
            bf16x8 ah[4];
            #pragma unroll
            for (int kc = 0; kc < 4; ++kc)
                ah[kc] = *(const bf16x8*)&s_hist[t - 1][c16 * ROWS + kc * 32 + quad * 8];
            #pragma unroll
            for (int kc = 0; kc < 4; ++kc) {
                az  = MFMA(ah[kc], Bzh[kc], az);
                ar  = MFMA(ah[kc], Brh[kc], ar);
                ach = MFMA(ah[kc], Bhh[kc], ach);
            }
        }

        // gates in-register (exp2-prescaled); h_t bf16 -> hist
        #pragma unroll
        for (int r = 0; r < 4; ++r) {
            uint2 Ec_ = Ecur[r];
            float zx = __uint_as_float(Ec_.x << 16);
            float rx = __uint_as_float(Ec_.x & 0xffff0000u);
            float xh = __uint_as_float(Ec_.y);            // scaled, bxh folded
            float z    = __builtin_amdgcn_rcpf(1.0f + vexp2n(az[r] + zx));
            float rr   = __builtin_amdgcn_rcpf(1.0f + vexp2n(ar[r] + rx));
            float e2   = vexp2(xh + rr * ach[r]);
            float cand = 1.0f - 2.0f * __builtin_amdgcn_rcpf(1.0f + e2);
            hA[r] = cand + z * (hA[r] - cand);
            s_hist[t][(quad * 4 + r) * ROWS + ucol] = f2bf(hA[r]);
        }
    };

    // consume cycle A,B,C; prefetch target = consume buffer of t+2
    #pragma unroll 1
    for (int t3 = 0; t3 < 5; ++t3) {
        window(3 * t3 + 0, Ea, Ec);
        window(3 * t3 + 1, Eb, Ea);
        window(3 * t3 + 2, Ec, Eb);
    }
    window(15, Ea, Ec);

    // ---------------- epilogue (one tile) ----------------
    // E0: h15 lo residual -> xb[0]
    #pragma unroll
    for (int r = 0; r < 4; ++r) {
        float hf = hA[r]; short hi = f2bf(hf);
        s_xb[0][(quad * 4 + r) * ROWS + ucol] = f2bf(hf - bf2f(hi));
    }
    __syncthreads();  // b1: hist[15] + residuals visible

    // E1: u = h15 @ Wqk (hi/lo split, 12 MFMAs)
    f32x4 uA = {0.f, 0.f, 0.f, 0.f};
    #pragma unroll
    for (int kc = 0; kc < 4; ++kc) {
        bf16x8 bqh = *(const bf16x8*)&wpk[(((24 + kc) * 8 + w) * 64 + lane) * 8];
        bf16x8 bql = *(const bf16x8*)&wpk[(((28 + kc) * 8 + w) * 64 + lane) * 8];
        bf16x8 Ah  = *(const bf16x8*)&s_hist[15][c16 * ROWS + kc * 32 + quad * 8];
        bf16x8 Al  = *(const bf16x8*)&s_xb[0][c16 * ROWS + kc * 32 + quad * 8];
        uA = MFMA(Ah, bqh, uA); uA = MFMA(Ah, bql, uA); uA = MFMA(Al, bqh, uA);
    }
    __syncthreads();  // b2: E1's xb reads done

    // E2: u hi/lo (C-scatter)
    #pragma unroll
    for (int r = 0; r < 4; ++r) {
        int off = (quad * 4 + r) * ROWS + ucol;
        float v = uA[r]; short hi = f2bf(v);
        s_xb[0][off] = hi; s_xb[1][off] = f2bf(v - bf2f(hi));
    }
    __syncthreads();  // b3

    // E3: att[p][l] = diag(U @ H_l^T) via MFMA; wave w does l = 2w, 2w+1.
    // A = u hi/lo (xb, E1 pattern); B[k][n] = h_l[n][k] (row-major hist read).
    // Diag element (p,p): thread quad==p>>2, reg p&3, col c16==p.
    {
        bf16x8 Uh[4], Ul[4];
        #pragma unroll
        for (int kc = 0; kc < 4; ++kc) {
            Uh[kc] = *(const bf16x8*)&s_xb[0][c16 * ROWS + kc * 32 + quad * 8];
            Ul[kc] = *(const bf16x8*)&s_xb[1][c16 * ROWS + kc * 32 + quad * 8];
        }
        #pragma unroll
        for (int li = 0; li < 2; ++li) {
            int l = 2 * w + li;
            f32x4 acc = {0.f, 0.f, 0.f, 0.f};
            #pragma unroll
            for (int kc = 0; kc < 4; ++kc) {
                bf16x8 Bh = *(const bf16x8*)&s_hist[l][c16 * ROWS + kc * 32 + quad * 8];
                acc = MFMA(Uh[kc], Bh, acc);
                acc = MFMA(Ul[kc], Bh, acc);
            }
            float d01 = (c16 & 1) ? acc[1] : acc[0];
            float d23 = (c16 & 1) ? acc[3] : acc[2];
            float dv  = (c16 & 2) ? d23 : d01;
            if (quad == (c16 >> 2)) s_att[c16][l] = dv;
        }
    }
    __syncthreads();  // b4

    // E4: ctx[p][v] = sum_l att[p][l] * hist_l[p][v]; hi/lo split
    // all 512 threads: 4 cols each
    {
        int p = tid >> 5, c0 = (tid & 31) * 4;
        float ctx[4] = {0.f, 0.f, 0.f, 0.f};
        #pragma unroll
        for (int l = 0; l < 16; ++l) {
            float al = s_att[p][l];
            bf16x4 hv = *(const bf16x4*)&s_hist[l][p * ROWS + c0];
            #pragma unroll
            for (int j = 0; j < 4; ++j) ctx[j] += al * bf2f(hv[j]);
        }
        #pragma unroll
        for (int j = 0; j < 4; ++j) {
            short hi = f2bf(ctx[j]);
            s_xb[0][p * ROWS + c0 + j] = hi;
            s_xb[1][p * ROWS + c0 + j] = f2bf(ctx[j] - bf2f(hi));
        }
    }
    __syncthreads();  // b5

    // E5: out = ctx @ wv (hi/lo split)
    f32x4 oA = {0.f, 0.f, 0.f, 0.f};
    #pragma unroll
    for (int kc = 0; kc < 4; ++kc) {
        bf16x8 bwh = *(const bf16x8*)&wpk[(((32 + kc) * 8 + w) * 64 + lane) * 8];
        bf16x8 bwl = *(const bf16x8*)&wpk[(((36 + kc) * 8 + w) * 64 + lane) * 8];
        bf16x8 Ah  = *(const bf16x8*)&s_xb[0][c16 * ROWS + kc * 32 + quad * 8];
        bf16x8 Al  = *(const bf16x8*)&s_xb[1][c16 * ROWS + kc * 32 + quad * 8];
        oA = MFMA(Ah, bwh, oA); oA = MFMA(Ah, bwl, oA); oA = MFMA(Al, bwh, oA);
    }
    #pragma unroll
    for (int r = 0; r < 4; ++r)
        out[(p0 + quad * 4 + r) * 128 + ucol] = oA[r];
}

extern "C" void kernel_launch(void* const* d_in, const int* in_sizes, int n_in,
                              void* d_out, int out_size, void* d_ws, size_t ws_size,
                              hipStream_t stream) {
    const float* inputs = (const float*)d_in[0];
    const int*   paths  = (const int*)d_in[1];
    // d_in[2]=idx, d_in[3]=seqs: layout known (p*16+s), unused
    const float* wx  = (const float*)d_in[4];
    const float* wr  = (const float*)d_in[5];
    const float* bi  = (const float*)d_in[6];
    const float* br  = (const float*)d_in[7];
    const float* wq  = (const float*)d_in[8];
    const float* wk  = (const float*)d_in[9];
    const float* wvp = (const float*)d_in[10];

    // workspace: E8 10,240,000 B | wpk 327,680 B  (total ~10.6 MB)
    char* ws = (char*)d_ws;
    uint2* E8 = (uint2*)ws;
    short* wpk = (short*)(ws + 10240000);

    int prep_n = GRU_T + QK_T + WV_T;
    prep_kernel<<<(prep_n + 255) / 256, 256, 0, stream>>>(wx, wr, wq, wk, wvp, wpk);
    eprep_kernel<<<NEDGES / 16, 512, 0, stream>>>(inputs, wpk, bi, E8);
    path_emb_kernel<<<NTILES, 512, 0, stream>>>(paths, wpk, E8, bi, br, (float*)d_out);
}

// Round 11
// 190.577 us; speedup vs baseline: 1.0776x; 1.0259x over previous
//
#include <hip/hip_runtime.h>

// PathEmbedding fused kernel for MI355X (gfx950). Round 19.
//
// Math (exact restructure): att[p,l] = h_l . u_p, u_p = h15 @ Wqk,
// Wqk[k][i] = sum_v wq[k,v] wk[i,v]; context = (sum_l att_l h_l) @ wv.
//
// R19: R12/R14 verified-best body (setprio RESTORED: R18 measured its
// removal at 115 vs 112) + FULL UNROLL of the 16-window loop -- the one
// change from the R13 bundle never isolated (R13's container death was
// confounded; R14 cleared the waves_per_eu half as a no-op).
// Full unroll: t compile-time -> hist ds offsets become immediates
// (t<=14 fits 16-bit ds offset), paths loads base+imm, loop control gone.
// Hand count: ~220 VALU issues/wave-window measured vs ~130 intrinsic;
// the delta is rolled-loop address recompute. NAMED Ea/Eb/Ec rotation is
// scratch-safe under unroll (R10's bug was the t%3 ARRAY, not unrolling).
// R18 lesson: setprio worth ~3us here (m190's lockstep-negative didn't hold).
// R17 LESSON: operand-role swap cut VALU 52->41% but LOST 12% -- kernel
// sits at a multi-resource balance point (LDS h-broadcast, MFMA, gates,
// barrier convoy); cutting one pipe can lengthen the critical path.
// R16 lesson: lgkmcnt-only barrier neutral; vmcnt-drain theory dead.
// R15 LESSON: reg file at the 128-reg boundary (64 VGPR + ~64 AGPR);
// ANY added pipeline state spills (WRITE 26->196MB tripwire).
// R12 lesson: exp2-prescaled gates + MFMA-diag E3 cut VALU 60->51%.
// R10 LESSON: rotation arrays (buf[t%N]) -> SCRATCH; only NAMED arrays
// passed as lambda args are promoted.
// R9 lesson: 2 WG/CU (LDS <= 80KB). R8: x-side precompute in E8.
// Fragment layouts (HW-verified): A[m=lane&15][k=quad*8+j],
// B[k=quad*8+j][n=lane&15], C/D[row=quad*4+reg][col=lane&15].

#define NUM_PATHS 30000
#define T 16
#define NTILES 1875
#define NEDGES 10000

#define SC1 1.4426950408889634f   // log2(e)
#define SC2 2.8853900817779268f   // 2*log2(e)

typedef float f32x4 __attribute__((ext_vector_type(4)));
typedef short bf16x8 __attribute__((ext_vector_type(8)));
typedef short bf16x4 __attribute__((ext_vector_type(4)));

// half-up rounding: max error 0.5 ulp, 2 VALU ops
__device__ __forceinline__ short f2bf(float f) {
    union { float f; unsigned u; } v; v.f = f;
    return (short)((v.u + 0x8000u) >> 16);
}
__device__ __forceinline__ float bf2f(short s) {
    union { unsigned u; float f; } v; v.u = ((unsigned)(unsigned short)s) << 16;
    return v.f;
}
// raw v_exp_f32 (2^x). neg variant uses the free VOP3 input modifier.
__device__ __forceinline__ float vexp2(float x) {
    float r; asm("v_exp_f32 %0, %1" : "=v"(r) : "v"(x)); return r;
}
__device__ __forceinline__ float vexp2n(float x) {
    float r; asm("v_exp_f32 %0, -%1" : "=v"(r) : "v"(x)); return r;
}

#define MFMA(a, b, c) __builtin_amdgcn_mfma_f32_16x16x32_bf16((a), (b), (c), 0, 0, 0)

// ---------- prep: packed B-frags only ----------
// wpk frag slot f, element ((f*8 + w)*64 + lane)*8 + j :
//   f 0..7  = Bz[kc] (k over [x;h])   f 8..15 = Br[kc]      (scaled SC1)
//   f 16..19= Bxh[kc] (x side)        f 20..23 = Bhh[kc]    (scaled SC2)
//   f 24..27= Bqk_hi[kc]              f 28..31 = Bqk_lo[kc]   (Wqk = wq.wk^T)
//   f 32..35= Bwv_hi[kc]              f 36..39 = Bwv_lo[kc]
#define GRU_T 12288
#define QK_T 16384
#define WV_T 2048
__global__ void prep_kernel(const float* __restrict__ Wx, const float* __restrict__ Wr,
                            const float* __restrict__ wq, const float* __restrict__ wk,
                            const float* __restrict__ wv,
                            short* __restrict__ wpk) {
    int id = blockIdx.x * 256 + threadIdx.x;
    if (id < GRU_T) {
        int f = id >> 9, rem = id & 511;
        int w = rem >> 6, lane = rem & 63;
        int quad = lane >> 4, c16 = lane & 15;
        int col = 16 * w + c16;
        short o[8];
        #pragma unroll
        for (int j = 0; j < 8; ++j) {
            float v;
            if (f < 16) {
                int k = (f & 7) * 32 + quad * 8 + j;          // 0..255 over [x;h]
                int cc = col + ((f < 8) ? 0 : 128);
                v = ((k < 128) ? Wx[k * 384 + cc] : Wr[(k - 128) * 384 + cc]) * SC1;
            } else {
                int k = ((f - 16) & 3) * 32 + quad * 8 + j;   // 0..127
                v = ((f < 20) ? Wx[k * 384 + 256 + col] : Wr[k * 384 + 256 + col]) * SC2;
            }
            o[j] = f2bf(v);
        }
        *(bf16x8*)&wpk[id * 8] = *(bf16x8*)o;
        return;
    }
    if (id < GRU_T + QK_T) {
        int t2 = id - GRU_T;
        int j = t2 & 7, lane = (t2 >> 3) & 63, w = (t2 >> 9) & 7, kc = t2 >> 12;
        int quad = lane >> 4, c16 = lane & 15, col = 16 * w + c16;
        int k = kc * 32 + quad * 8 + j;
        const float* qr = wq + k * 128;
        const float* kr = wk + col * 128;
        float s = 0.f;
        #pragma unroll 8
        for (int vv = 0; vv < 128; ++vv) s += qr[vv] * kr[vv];
        short hi = f2bf(s);
        wpk[(((24 + kc) * 8 + w) * 64 + lane) * 8 + j] = hi;
        wpk[(((28 + kc) * 8 + w) * 64 + lane) * 8 + j] = f2bf(s - bf2f(hi));
        return;
    }
    if (id < GRU_T + QK_T + WV_T) {
        int t2 = id - GRU_T - QK_T;
        int lane = t2 & 63, w = (t2 >> 6) & 7, kc = t2 >> 9;
        int quad = lane >> 4, c16 = lane & 15, col = 16 * w + c16;
        short hi8[8], lo8[8];
        #pragma unroll
        for (int j = 0; j < 8; ++j) {
            float v = wv[(kc * 32 + quad * 8 + j) * 128 + col];
            hi8[j] = f2bf(v);
            lo8[j] = f2bf(v - bf2f(hi8[j]));
        }
        *(bf16x8*)&wpk[(((32 + kc) * 8 + w) * 64 + lane) * 8] = *(bf16x8*)hi8;
        *(bf16x8*)&wpk[(((36 + kc) * 8 + w) * 64 + lane) * 8] = *(bf16x8*)lo8;
    }
}

// ---------- eprep: E8[e*128 + ucol] = {pack(z,r) bf16x2, xh'+bxh' f32} ----------
// Preacts come out pre-scaled (weights scaled in prep); bxh scaled here.
__global__ __launch_bounds__(512) void eprep_kernel(
    const float* __restrict__ inputs, const short* __restrict__ wpk,
    const float* __restrict__ bias_i, uint2* __restrict__ E8) {
    const int w = threadIdx.x >> 6, lane = threadIdx.x & 63;
    const int quad = lane >> 4, c16 = lane & 15;
    const int ucol = 16 * w + c16;
    const int e0 = blockIdx.x * 16;

    const float bxh = bias_i[256 + ucol] * SC2;

    bf16x8 A[4];
    const float* row = inputs + (e0 + c16) * 128;
    #pragma unroll
    for (int kc = 0; kc < 4; ++kc) {
        float4 a = *(const float4*)&row[kc * 32 + quad * 8];
        float4 b = *(const float4*)&row[kc * 32 + quad * 8 + 4];
        short o[8] = {f2bf(a.x), f2bf(a.y), f2bf(a.z), f2bf(a.w),
                      f2bf(b.x), f2bf(b.y), f2bf(b.z), f2bf(b.w)};
        A[kc] = *(bf16x8*)o;
    }
    f32x4 az = {0.f, 0.f, 0.f, 0.f}, ar = az, ax = az;
    #pragma unroll
    for (int kc = 0; kc < 4; ++kc) {
        bf16x8 Bz = *(const bf16x8*)&wpk[(((0 + kc) * 8 + w) * 64 + lane) * 8];
        bf16x8 Br = *(const bf16x8*)&wpk[(((8 + kc) * 8 + w) * 64 + lane) * 8];
        bf16x8 Bx = *(const bf16x8*)&wpk[(((16 + kc) * 8 + w) * 64 + lane) * 8];
        az = MFMA(A[kc], Bz, az);
        ar = MFMA(A[kc], Br, ar);
        ax = MFMA(A[kc], Bx, ax);
    }
    #pragma unroll
    for (int r = 0; r < 4; ++r) {
        unsigned zr = (unsigned)(unsigned short)f2bf(az[r]) |
                      ((unsigned)(unsigned short)f2bf(ar[r]) << 16);
        uint2 val;
        val.x = zr;
        val.y = __float_as_uint(ax[r] + bxh);
        E8[(e0 + quad * 4 + r) * 128 + ucol] = val;
    }
}

#define ROWS 136    // padded row stride (shorts): <=2-way LDS conflicts
#define HSLOT 2184  // 16*136+8: +4-word slot rotation

__global__ __launch_bounds__(512, 4) void path_emb_kernel(
    const int* __restrict__ paths, const short* __restrict__ wpk,
    const uint2* __restrict__ E8,
    const float* __restrict__ bias_i, const float* __restrict__ bias_r,
    float* __restrict__ out)
{
    __shared__ __align__(16) short s_hist[16][HSLOT]; // h history, one tile (69,888 B)
    __shared__ __align__(16) short s_xb[2][T * ROWS]; // epilogue bufs       (8,704 B)
    __shared__ float s_att[16][20];                   // att                 (1,280 B)
    // total 79,872 B -> 2 WG/CU (16 waves/CU = 4 waves/EU)

    const int tid  = threadIdx.x;
    const int w    = tid >> 6;
    const int lane = tid & 63;
    const int quad = lane >> 4;
    const int c16  = lane & 15;
    const int ucol = 16 * w + c16;

    const float bz  = (bias_i[ucol] + bias_r[ucol]) * SC1;
    const float brr = (bias_i[128 + ucol] + bias_r[128 + ucol]) * SC1;
    const float bhh = bias_r[256 + ucol] * SC2;

    // persistent h-side GRU B-frags (live in AGPRs; R15 lesson)
    bf16x8 Bzh[4], Brh[4], Bhh[4];
    #pragma unroll
    for (int kc = 0; kc < 4; ++kc) {
        Bzh[kc] = *(const bf16x8*)&wpk[(((4 + kc)  * 8 + w) * 64 + lane) * 8];
        Brh[kc] = *(const bf16x8*)&wpk[(((12 + kc) * 8 + w) * 64 + lane) * 8];
        Bhh[kc] = *(const bf16x8*)&wpk[(((20 + kc) * 8 + w) * 64 + lane) * 8];
    }

    const int p0 = blockIdx.x * T;

    float hA[4] = {0.f, 0.f, 0.f, 0.f};

    // one base pointer for this thread's 4 path rows; all loads base+imm
    const int* pbase = paths + (p0 + quad * 4) * 16;
    const uint2* Erow = E8 + ucol;

    // ---- 2-deep pipeline: three NAMED buffers, rotated via lambda args ----
    uint2 Ea[4], Eb[4], Ec[4];

    { // prologue: E(0)->Ea, E(1)->Eb
        int id0[4], id1[4];
        #pragma unroll
        for (int i = 0; i < 4; ++i) id0[i] = pbase[i * 16 + 0];
        #pragma unroll
        for (int i = 0; i < 4; ++i) id1[i] = pbase[i * 16 + 1];
        #pragma unroll
        for (int i = 0; i < 4; ++i) Ea[i] = Erow[id0[i] * 128];
        #pragma unroll
        for (int i = 0; i < 4; ++i) Eb[i] = Erow[id1[i] * 128];
    }

    // window t (compile-time under full unroll): consume Ecur=E(t);
    // issue id(t+2)->E(t+2) chain into Enxt.
    auto window = [&](int t, uint2* Ecur, uint2* Enxt) {
        __syncthreads();  // h_{t-1} writes (all waves) visible

        if (t < 14) {
            int en[4];
            #pragma unroll
            for (int i = 0; i < 4; ++i)
                en[i] = pbase[i * 16 + t + 2];
            #pragma unroll
            for (int i = 0; i < 4; ++i) Enxt[i] = Erow[en[i] * 128];
        }

        f32x4 az  = {bz, bz, bz, bz};
        f32x4 ar  = {brr, brr, brr, brr};
        f32x4 ach = {bhh, bhh, bhh, bhh};

        if (t > 0) {
            bf16x8 ah[4];
            #pragma unroll
            for (int kc = 0; kc < 4; ++kc)
                ah[kc] = *(const bf16x8*)&s_hist[t - 1][c16 * ROWS + kc * 32 + quad * 8];
            __builtin_amdgcn_s_setprio(1);
            #pragma unroll
            for (int kc = 0; kc < 4; ++kc) {
                az  = MFMA(ah[kc], Bzh[kc], az);
                ar  = MFMA(ah[kc], Brh[kc], ar);
                ach = MFMA(ah[kc], Bhh[kc], ach);
            }
            __builtin_amdgcn_s_setprio(0);
        }

        // gates in-register (exp2-prescaled); h_t bf16 -> hist
        #pragma unroll
        for (int r = 0; r < 4; ++r) {
            uint2 Ec_ = Ecur[r];
            float zx = __uint_as_float(Ec_.x << 16);
            float rx = __uint_as_float(Ec_.x & 0xffff0000u);
            float xh = __uint_as_float(Ec_.y);            // scaled, bxh folded
            float z    = __builtin_amdgcn_rcpf(1.0f + vexp2n(az[r] + zx));
            float rr   = __builtin_amdgcn_rcpf(1.0f + vexp2n(ar[r] + rx));
            float e2   = vexp2(xh + rr * ach[r]);
            float cand = 1.0f - 2.0f * __builtin_amdgcn_rcpf(1.0f + e2);
            hA[r] = cand + z * (hA[r] - cand);
            s_hist[t][(quad * 4 + r) * ROWS + ucol] = f2bf(hA[r]);
        }
    };

    // FULL unroll: t compile-time in every window copy (R19's one change).
    // Named buffer rotation stays static per emitted window (R10-safe).
    #pragma unroll
    for (int t3 = 0; t3 < 5; ++t3) {
        window(3 * t3 + 0, Ea, Ec);
        window(3 * t3 + 1, Eb, Ea);
        window(3 * t3 + 2, Ec, Eb);
    }
    window(15, Ea, Ec);

    // ---------------- epilogue (one tile) ----------------
    // E0: h15 lo residual -> xb[0]
    #pragma unroll
    for (int r = 0; r < 4; ++r) {
        float hf = hA[r]; short hi = f2bf(hf);
        s_xb[0][(quad * 4 + r) * ROWS + ucol] = f2bf(hf - bf2f(hi));
    }
    __syncthreads();  // b1: hist[15] + residuals visible

    // E1: u = h15 @ Wqk (hi/lo split, 12 MFMAs)
    f32x4 uA = {0.f, 0.f, 0.f, 0.f};
    #pragma unroll
    for (int kc = 0; kc < 4; ++kc) {
        bf16x8 bqh = *(const bf16x8*)&wpk[(((24 + kc) * 8 + w) * 64 + lane) * 8];
        bf16x8 bql = *(const bf16x8*)&wpk[(((28 + kc) * 8 + w) * 64 + lane) * 8];
        bf16x8 Ah  = *(const bf16x8*)&s_hist[15][c16 * ROWS + kc * 32 + quad * 8];
        bf16x8 Al  = *(const bf16x8*)&s_xb[0][c16 * ROWS + kc * 32 + quad * 8];
        uA = MFMA(Ah, bqh, uA); uA = MFMA(Ah, bql, uA); uA = MFMA(Al, bqh, uA);
    }
    __syncthreads();  // b2: E1's xb reads done

    // E2: u hi/lo (C-scatter)
    #pragma unroll
    for (int r = 0; r < 4; ++r) {
        int off = (quad * 4 + r) * ROWS + ucol;
        float v = uA[r]; short hi = f2bf(v);
        s_xb[0][off] = hi; s_xb[1][off] = f2bf(v - bf2f(hi));
    }
    __syncthreads();  // b3

    // E3: att[p][l] = diag(U @ H_l^T) via MFMA; wave w does l = 2w, 2w+1.
    // A = u hi/lo (xb, E1 pattern); B[k][n] = h_l[n][k] (row-major hist read).
    // Diag element (p,p): thread quad==p>>2, reg p&3, col c16==p.
    {
        bf16x8 Uh[4], Ul[4];
        #pragma unroll
        for (int kc = 0; kc < 4; ++kc) {
            Uh[kc] = *(const bf16x8*)&s_xb[0][c16 * ROWS + kc * 32 + quad * 8];
            Ul[kc] = *(const bf16x8*)&s_xb[1][c16 * ROWS + kc * 32 + quad * 8];
        }
        #pragma unroll
        for (int li = 0; li < 2; ++li) {
            int l = 2 * w + li;
            f32x4 acc = {0.f, 0.f, 0.f, 0.f};
            #pragma unroll
            for (int kc = 0; kc < 4; ++kc) {
                bf16x8 Bh = *(const bf16x8*)&s_hist[l][c16 * ROWS + kc * 32 + quad * 8];
                acc = MFMA(Uh[kc], Bh, acc);
                acc = MFMA(Ul[kc], Bh, acc);
            }
            float d01 = (c16 & 1) ? acc[1] : acc[0];
            float d23 = (c16 & 1) ? acc[3] : acc[2];
            float dv  = (c16 & 2) ? d23 : d01;
            if (quad == (c16 >> 2)) s_att[c16][l] = dv;
        }
    }
    __syncthreads();  // b4

    // E4: ctx[p][v] = sum_l att[p][l] * hist_l[p][v]; hi/lo split
    // all 512 threads: 4 cols each
    {
        int p = tid >> 5, c0 = (tid & 31) * 4;
        float ctx[4] = {0.f, 0.f, 0.f, 0.f};
        #pragma unroll
        for (int l = 0; l < 16; ++l) {
            float al = s_att[p][l];
            bf16x4 hv = *(const bf16x4*)&s_hist[l][p * ROWS + c0];
            #pragma unroll
            for (int j = 0; j < 4; ++j) ctx[j] += al * bf2f(hv[j]);
        }
        #pragma unroll
        for (int j = 0; j < 4; ++j) {
            short hi = f2bf(ctx[j]);
            s_xb[0][p * ROWS + c0 + j] = hi;
            s_xb[1][p * ROWS + c0 + j] = f2bf(ctx[j] - bf2f(hi));
        }
    }
    __syncthreads();  // b5

    // E5: out = ctx @ wv (hi/lo split)
    f32x4 oA = {0.f, 0.f, 0.f, 0.f};
    #pragma unroll
    for (int kc = 0; kc < 4; ++kc) {
        bf16x8 bwh = *(const bf16x8*)&wpk[(((32 + kc) * 8 + w) * 64 + lane) * 8];
        bf16x8 bwl = *(const bf16x8*)&wpk[(((36 + kc) * 8 + w) * 64 + lane) * 8];
        bf16x8 Ah  = *(const bf16x8*)&s_xb[0][c16 * ROWS + kc * 32 + quad * 8];
        bf16x8 Al  = *(const bf16x8*)&s_xb[1][c16 * ROWS + kc * 32 + quad * 8];
        oA = MFMA(Ah, bwh, oA); oA = MFMA(Ah, bwl, oA); oA = MFMA(Al, bwh, oA);
    }
    #pragma unroll
    for (int r = 0; r < 4; ++r)
        out[(p0 + quad * 4 + r) * 128 + ucol] = oA[r];
}

extern "C" void kernel_launch(void* const* d_in, const int* in_sizes, int n_in,
                              void* d_out, int out_size, void* d_ws, size_t ws_size,
                              hipStream_t stream) {
    const float* inputs = (const float*)d_in[0];
    const int*   paths  = (const int*)d_in[1];
    // d_in[2]=idx, d_in[3]=seqs: layout known (p*16+s), unused
    const float* wx  = (const float*)d_in[4];
    const float* wr  = (const float*)d_in[5];
    const float* bi  = (const float*)d_in[6];
    const float* br  = (const float*)d_in[7];
    const float* wq  = (const float*)d_in[8];
    const float* wk  = (const float*)d_in[9];
    const float* wvp = (const float*)d_in[10];

    // workspace: E8 10,240,000 B | wpk 327,680 B  (total ~10.6 MB)
    char* ws = (char*)d_ws;
    uint2* E8 = (uint2*)ws;
    short* wpk = (short*)(ws + 10240000);

    int prep_n = GRU_T + QK_T + WV_T;
    prep_kernel<<<(prep_n + 255) / 256, 256, 0, stream>>>(wx, wr, wq, wk, wvp, wpk);
    eprep_kernel<<<NEDGES / 16, 512, 0, stream>>>(inputs, wpk, bi, E8);
    path_emb_kernel<<<NTILES, 512, 0, stream>>>(paths, wpk, E8, bi, br, (float*)d_out);
}

// Round 12
// 190.073 us; speedup vs baseline: 1.0805x; 1.0026x over previous
//
#include <hip/hip_runtime.h>

// PathEmbedding fused kernel for MI355X (gfx950). Round 20.
//
// Math (exact restructure): att[p,l] = h_l . u_p, u_p = h15 @ Wqk,
// Wqk[k][i] = sum_v wq[k,v] wk[i,v]; context = (sum_l att_l h_l) @ wv.
//
// R20: micro-harvest on the R19-verified body (109.7us):
//  - t=0 barrier removed (dead since R9's one-tile-per-block: no prior
//    epilogue WAR on s_hist, window 0 reads no hist). if(t>0) under unroll.
//  - E4 rewrite: att row read as 4x ds_read_b128 (broadcast, 16B-aligned)
//    instead of 16x ds_read_b32; ctx hi/lo stores packed via
//    v_cvt_pk_bf16_f32 + 2x ds_write_b64 (8B-aligned) instead of
//    8x (f2bf + ds_write_b16). ~150 -> ~120 VALU+ds per thread in E4.
//    lo residual computed from the SAME RNE hi -> rounding self-consistent.
// R19 lesson: full unroll real but small (-2%); compiler already hoisted
// most address math. R18 lesson: setprio worth ~3us, KEEP.
// R17 LESSON: operand-role swap cut VALU 52->41% but LOST 12% -- kernel
// sits at a multi-resource balance point; cutting one pipe can lengthen
// the critical path. R16: lgkmcnt-only barrier neutral.
// R15 LESSON: reg file at the 128-reg boundary (64 VGPR + ~64 AGPR);
// ANY added pipeline state spills (WRITE 26->196MB tripwire).
// R12 lesson: exp2-prescaled gates + MFMA-diag E3 cut VALU 60->51%.
// R10 LESSON: rotation arrays (buf[t%N]) -> SCRATCH; only NAMED arrays
// passed as lambda args are promoted.
// R9 lesson: 2 WG/CU (LDS <= 80KB). R8: x-side precompute in E8.
// Fragment layouts (HW-verified): A[m=lane&15][k=quad*8+j],
// B[k=quad*8+j][n=lane&15], C/D[row=quad*4+reg][col=lane&15].

#define NUM_PATHS 30000
#define T 16
#define NTILES 1875
#define NEDGES 10000

#define SC1 1.4426950408889634f   // log2(e)
#define SC2 2.8853900817779268f   // 2*log2(e)

typedef float f32x4 __attribute__((ext_vector_type(4)));
typedef short bf16x8 __attribute__((ext_vector_type(8)));
typedef short bf16x4 __attribute__((ext_vector_type(4)));

// half-up rounding: max error 0.5 ulp, 2 VALU ops
__device__ __forceinline__ short f2bf(float f) {
    union { float f; unsigned u; } v; v.f = f;
    return (short)((v.u + 0x8000u) >> 16);
}
__device__ __forceinline__ float bf2f(short s) {
    union { unsigned u; float f; } v; v.u = ((unsigned)(unsigned short)s) << 16;
    return v.f;
}
// raw v_exp_f32 (2^x). neg variant uses the free VOP3 input modifier.
__device__ __forceinline__ float vexp2(float x) {
    float r; asm("v_exp_f32 %0, %1" : "=v"(r) : "v"(x)); return r;
}
__device__ __forceinline__ float vexp2n(float x) {
    float r; asm("v_exp_f32 %0, -%1" : "=v"(r) : "v"(x)); return r;
}
// packed f32->2xbf16 (RNE): dst.lo = bf16(a), dst.hi = bf16(b)
__device__ __forceinline__ unsigned cvtpk(float a, float b) {
    unsigned r; asm("v_cvt_pk_bf16_f32 %0, %1, %2" : "=v"(r) : "v"(a), "v"(b));
    return r;
}

#define MFMA(a, b, c) __builtin_amdgcn_mfma_f32_16x16x32_bf16((a), (b), (c), 0, 0, 0)

// ---------- prep: packed B-frags only ----------
// wpk frag slot f, element ((f*8 + w)*64 + lane)*8 + j :
//   f 0..7  = Bz[kc] (k over [x;h])   f 8..15 = Br[kc]      (scaled SC1)
//   f 16..19= Bxh[kc] (x side)        f 20..23 = Bhh[kc]    (scaled SC2)
//   f 24..27= Bqk_hi[kc]              f 28..31 = Bqk_lo[kc]   (Wqk = wq.wk^T)
//   f 32..35= Bwv_hi[kc]              f 36..39 = Bwv_lo[kc]
#define GRU_T 12288
#define QK_T 16384
#define WV_T 2048
__global__ void prep_kernel(const float* __restrict__ Wx, const float* __restrict__ Wr,
                            const float* __restrict__ wq, const float* __restrict__ wk,
                            const float* __restrict__ wv,
                            short* __restrict__ wpk) {
    int id = blockIdx.x * 256 + threadIdx.x;
    if (id < GRU_T) {
        int f = id >> 9, rem = id & 511;
        int w = rem >> 6, lane = rem & 63;
        int quad = lane >> 4, c16 = lane & 15;
        int col = 16 * w + c16;
        short o[8];
        #pragma unroll
        for (int j = 0; j < 8; ++j) {
            float v;
            if (f < 16) {
                int k = (f & 7) * 32 + quad * 8 + j;          // 0..255 over [x;h]
                int cc = col + ((f < 8) ? 0 : 128);
                v = ((k < 128) ? Wx[k * 384 + cc] : Wr[(k - 128) * 384 + cc]) * SC1;
            } else {
                int k = ((f - 16) & 3) * 32 + quad * 8 + j;   // 0..127
                v = ((f < 20) ? Wx[k * 384 + 256 + col] : Wr[k * 384 + 256 + col]) * SC2;
            }
            o[j] = f2bf(v);
        }
        *(bf16x8*)&wpk[id * 8] = *(bf16x8*)o;
        return;
    }
    if (id < GRU_T + QK_T) {
        int t2 = id - GRU_T;
        int j = t2 & 7, lane = (t2 >> 3) & 63, w = (t2 >> 9) & 7, kc = t2 >> 12;
        int quad = lane >> 4, c16 = lane & 15, col = 16 * w + c16;
        int k = kc * 32 + quad * 8 + j;
        const float* qr = wq + k * 128;
        const float* kr = wk + col * 128;
        float s = 0.f;
        #pragma unroll 8
        for (int vv = 0; vv < 128; ++vv) s += qr[vv] * kr[vv];
        short hi = f2bf(s);
        wpk[(((24 + kc) * 8 + w) * 64 + lane) * 8 + j] = hi;
        wpk[(((28 + kc) * 8 + w) * 64 + lane) * 8 + j] = f2bf(s - bf2f(hi));
        return;
    }
    if (id < GRU_T + QK_T + WV_T) {
        int t2 = id - GRU_T - QK_T;
        int lane = t2 & 63, w = (t2 >> 6) & 7, kc = t2 >> 9;
        int quad = lane >> 4, c16 = lane & 15, col = 16 * w + c16;
        short hi8[8], lo8[8];
        #pragma unroll
        for (int j = 0; j < 8; ++j) {
            float v = wv[(kc * 32 + quad * 8 + j) * 128 + col];
            hi8[j] = f2bf(v);
            lo8[j] = f2bf(v - bf2f(hi8[j]));
        }
        *(bf16x8*)&wpk[(((32 + kc) * 8 + w) * 64 + lane) * 8] = *(bf16x8*)hi8;
        *(bf16x8*)&wpk[(((36 + kc) * 8 + w) * 64 + lane) * 8] = *(bf16x8*)lo8;
    }
}

// ---------- eprep: E8[e*128 + ucol] = {pack(z,r) bf16x2, xh'+bxh' f32} ----------
// Preacts come out pre-scaled (weights scaled in prep); bxh scaled here.
__global__ __launch_bounds__(512) void eprep_kernel(
    const float* __restrict__ inputs, const short* __restrict__ wpk,
    const float* __restrict__ bias_i, uint2* __restrict__ E8) {
    const int w = threadIdx.x >> 6, lane = threadIdx.x & 63;
    const int quad = lane >> 4, c16 = lane & 15;
    const int ucol = 16 * w + c16;
    const int e0 = blockIdx.x * 16;

    const float bxh = bias_i[256 + ucol] * SC2;

    bf16x8 A[4];
    const float* row = inputs + (e0 + c16) * 128;
    #pragma unroll
    for (int kc = 0; kc < 4; ++kc) {
        float4 a = *(const float4*)&row[kc * 32 + quad * 8];
        float4 b = *(const float4*)&row[kc * 32 + quad * 8 + 4];
        short o[8] = {f2bf(a.x), f2bf(a.y), f2bf(a.z), f2bf(a.w),
                      f2bf(b.x), f2bf(b.y), f2bf(b.z), f2bf(b.w)};
        A[kc] = *(bf16x8*)o;
    }
    f32x4 az = {0.f, 0.f, 0.f, 0.f}, ar = az, ax = az;
    #pragma unroll
    for (int kc = 0; kc < 4; ++kc) {
        bf16x8 Bz = *(const bf16x8*)&wpk[(((0 + kc) * 8 + w) * 64 + lane) * 8];
        bf16x8 Br = *(const bf16x8*)&wpk[(((8 + kc) * 8 + w) * 64 + lane) * 8];
        bf16x8 Bx = *(const bf16x8*)&wpk[(((16 + kc) * 8 + w) * 64 + lane) * 8];
        az = MFMA(A[kc], Bz, az);
        ar = MFMA(A[kc], Br, ar);
        ax = MFMA(A[kc], Bx, ax);
    }
    #pragma unroll
    for (int r = 0; r < 4; ++r) {
        unsigned zr = (unsigned)(unsigned short)f2bf(az[r]) |
                      ((unsigned)(unsigned short)f2bf(ar[r]) << 16);
        uint2 val;
        val.x = zr;
        val.y = __float_as_uint(ax[r] + bxh);
        E8[(e0 + quad * 4 + r) * 128 + ucol] = val;
    }
}

#define ROWS 136    // padded row stride (shorts): <=2-way LDS conflicts
#define HSLOT 2184  // 16*136+8: +4-word slot rotation

__global__ __launch_bounds__(512, 4) void path_emb_kernel(
    const int* __restrict__ paths, const short* __restrict__ wpk,
    const uint2* __restrict__ E8,
    const float* __restrict__ bias_i, const float* __restrict__ bias_r,
    float* __restrict__ out)
{
    __shared__ __align__(16) short s_hist[16][HSLOT]; // h history, one tile (69,888 B)
    __shared__ __align__(16) short s_xb[2][T * ROWS]; // epilogue bufs       (8,704 B)
    __shared__ float s_att[16][20];                   // att                 (1,280 B)
    // total 79,872 B -> 2 WG/CU (16 waves/CU = 4 waves/EU)

    const int tid  = threadIdx.x;
    const int w    = tid >> 6;
    const int lane = tid & 63;
    const int quad = lane >> 4;
    const int c16  = lane & 15;
    const int ucol = 16 * w + c16;

    const float bz  = (bias_i[ucol] + bias_r[ucol]) * SC1;
    const float brr = (bias_i[128 + ucol] + bias_r[128 + ucol]) * SC1;
    const float bhh = bias_r[256 + ucol] * SC2;

    // persistent h-side GRU B-frags (live in AGPRs; R15 lesson)
    bf16x8 Bzh[4], Brh[4], Bhh[4];
    #pragma unroll
    for (int kc = 0; kc < 4; ++kc) {
        Bzh[kc] = *(const bf16x8*)&wpk[(((4 + kc)  * 8 + w) * 64 + lane) * 8];
        Brh[kc] = *(const bf16x8*)&wpk[(((12 + kc) * 8 + w) * 64 + lane) * 8];
        Bhh[kc] = *(const bf16x8*)&wpk[(((20 + kc) * 8 + w) * 64 + lane) * 8];
    }

    const int p0 = blockIdx.x * T;

    float hA[4] = {0.f, 0.f, 0.f, 0.f};

    // one base pointer for this thread's 4 path rows; all loads base+imm
    const int* pbase = paths + (p0 + quad * 4) * 16;
    const uint2* Erow = E8 + ucol;

    // ---- 2-deep pipeline: three NAMED buffers, rotated via lambda args ----
    uint2 Ea[4], Eb[4], Ec[4];

    { // prologue: E(0)->Ea, E(1)->Eb
        int id0[4], id1[4];
        #pragma unroll
        for (int i = 0; i < 4; ++i) id0[i] = pbase[i * 16 + 0];
        #pragma unroll
        for (int i = 0; i < 4; ++i) id1[i] = pbase[i * 16 + 1];
        #pragma unroll
        for (int i = 0; i < 4; ++i) Ea[i] = Erow[id0[i] * 128];
        #pragma unroll
        for (int i = 0; i < 4; ++i) Eb[i] = Erow[id1[i] * 128];
    }

    // window t (compile-time under full unroll): consume Ecur=E(t);
    // issue id(t+2)->E(t+2) chain into Enxt.
    auto window = [&](int t, uint2* Ecur, uint2* Enxt) {
        if (t > 0) __syncthreads();  // h_{t-1} visible; t=0 barrier is dead
                                     // (one tile/block: no prior LDS use)

        if (t < 14) {
            int en[4];
            #pragma unroll
            for (int i = 0; i < 4; ++i)
                en[i] = pbase[i * 16 + t + 2];
            #pragma unroll
            for (int i = 0; i < 4; ++i) Enxt[i] = Erow[en[i] * 128];
        }

        f32x4 az  = {bz, bz, bz, bz};
        f32x4 ar  = {brr, brr, brr, brr};
        f32x4 ach = {bhh, bhh, bhh, bhh};

        if (t > 0) {
            bf16x8 ah[4];
            #pragma unroll
            for (int kc = 0; kc < 4; ++kc)
                ah[kc] = *(const bf16x8*)&s_hist[t - 1][c16 * ROWS + kc * 32 + quad * 8];
            __builtin_amdgcn_s_setprio(1);
            #pragma unroll
            for (int kc = 0; kc < 4; ++kc) {
                az  = MFMA(ah[kc], Bzh[kc], az);
                ar  = MFMA(ah[kc], Brh[kc], ar);
                ach = MFMA(ah[kc], Bhh[kc], ach);
            }
            __builtin_amdgcn_s_setprio(0);
        }

        // gates in-register (exp2-prescaled); h_t bf16 -> hist
        #pragma unroll
        for (int r = 0; r < 4; ++r) {
            uint2 Ec_ = Ecur[r];
            float zx = __uint_as_float(Ec_.x << 16);
            float rx = __uint_as_float(Ec_.x & 0xffff0000u);
            float xh = __uint_as_float(Ec_.y);            // scaled, bxh folded
            float z    = __builtin_amdgcn_rcpf(1.0f + vexp2n(az[r] + zx));
            float rr   = __builtin_amdgcn_rcpf(1.0f + vexp2n(ar[r] + rx));
            float e2   = vexp2(xh + rr * ach[r]);
            float cand = 1.0f - 2.0f * __builtin_amdgcn_rcpf(1.0f + e2);
            hA[r] = cand + z * (hA[r] - cand);
            s_hist[t][(quad * 4 + r) * ROWS + ucol] = f2bf(hA[r]);
        }
    };

    // FULL unroll (R19): t compile-time in every window copy.
    // Named buffer rotation stays static per emitted window (R10-safe).
    #pragma unroll
    for (int t3 = 0; t3 < 5; ++t3) {
        window(3 * t3 + 0, Ea, Ec);
        window(3 * t3 + 1, Eb, Ea);
        window(3 * t3 + 2, Ec, Eb);
    }
    window(15, Ea, Ec);

    // ---------------- epilogue (one tile) ----------------
    // E0: h15 lo residual -> xb[0]
    #pragma unroll
    for (int r = 0; r < 4; ++r) {
        float hf = hA[r]; short hi = f2bf(hf);
        s_xb[0][(quad * 4 + r) * ROWS + ucol] = f2bf(hf - bf2f(hi));
    }
    __syncthreads();  // b1: hist[15] + residuals visible

    // E1: u = h15 @ Wqk (hi/lo split, 12 MFMAs)
    f32x4 uA = {0.f, 0.f, 0.f, 0.f};
    #pragma unroll
    for (int kc = 0; kc < 4; ++kc) {
        bf16x8 bqh = *(const bf16x8*)&wpk[(((24 + kc) * 8 + w) * 64 + lane) * 8];
        bf16x8 bql = *(const bf16x8*)&wpk[(((28 + kc) * 8 + w) * 64 + lane) * 8];
        bf16x8 Ah  = *(const bf16x8*)&s_hist[15][c16 * ROWS + kc * 32 + quad * 8];
        bf16x8 Al  = *(const bf16x8*)&s_xb[0][c16 * ROWS + kc * 32 + quad * 8];
        uA = MFMA(Ah, bqh, uA); uA = MFMA(Ah, bql, uA); uA = MFMA(Al, bqh, uA);
    }
    __syncthreads();  // b2: E1's xb reads done

    // E2: u hi/lo (C-scatter)
    #pragma unroll
    for (int r = 0; r < 4; ++r) {
        int off = (quad * 4 + r) * ROWS + ucol;
        float v = uA[r]; short hi = f2bf(v);
        s_xb[0][off] = hi; s_xb[1][off] = f2bf(v - bf2f(hi));
    }
    __syncthreads();  // b3

    // E3: att[p][l] = diag(U @ H_l^T) via MFMA; wave w does l = 2w, 2w+1.
    // A = u hi/lo (xb, E1 pattern); B[k][n] = h_l[n][k] (row-major hist read).
    // Diag element (p,p): thread quad==p>>2, reg p&3, col c16==p.
    {
        bf16x8 Uh[4], Ul[4];
        #pragma unroll
        for (int kc = 0; kc < 4; ++kc) {
            Uh[kc] = *(const bf16x8*)&s_xb[0][c16 * ROWS + kc * 32 + quad * 8];
            Ul[kc] = *(const bf16x8*)&s_xb[1][c16 * ROWS + kc * 32 + quad * 8];
        }
        #pragma unroll
        for (int li = 0; li < 2; ++li) {
            int l = 2 * w + li;
            f32x4 acc = {0.f, 0.f, 0.f, 0.f};
            #pragma unroll
            for (int kc = 0; kc < 4; ++kc) {
                bf16x8 Bh = *(const bf16x8*)&s_hist[l][c16 * ROWS + kc * 32 + quad * 8];
                acc = MFMA(Uh[kc], Bh, acc);
                acc = MFMA(Ul[kc], Bh, acc);
            }
            float d01 = (c16 & 1) ? acc[1] : acc[0];
            float d23 = (c16 & 1) ? acc[3] : acc[2];
            float dv  = (c16 & 2) ? d23 : d01;
            if (quad == (c16 >> 2)) s_att[c16][l] = dv;
        }
    }
    __syncthreads();  // b4

    // E4: ctx[p][v] = sum_l att[p][l] * hist_l[p][v]; hi/lo split.
    // R20: att row via 4x ds_read_b128 (broadcast); packed cvt_pk stores
    // (2x ds_write_b64) replace 8x f2bf+ds_write_b16.
    {
        int p = tid >> 5, c0 = (tid & 31) * 4;
        float4 aa[4];
        #pragma unroll
        for (int q = 0; q < 4; ++q)
            aa[q] = *(const float4*)&s_att[p][q * 4];
        float ctx[4] = {0.f, 0.f, 0.f, 0.f};
        #pragma unroll
        for (int l = 0; l < 16; ++l) {
            float al = ((const float*)aa)[l];   // l compile-time: static idx
            bf16x4 hv = *(const bf16x4*)&s_hist[l][p * ROWS + c0];
            #pragma unroll
            for (int j = 0; j < 4; ++j) ctx[j] += al * bf2f(hv[j]);
        }
        uint2 hi, lo;
        hi.x = cvtpk(ctx[0], ctx[1]);
        hi.y = cvtpk(ctx[2], ctx[3]);
        float l0 = ctx[0] - __uint_as_float(hi.x << 16);
        float l1 = ctx[1] - __uint_as_float(hi.x & 0xffff0000u);
        float l2 = ctx[2] - __uint_as_float(hi.y << 16);
        float l3 = ctx[3] - __uint_as_float(hi.y & 0xffff0000u);
        lo.x = cvtpk(l0, l1);
        lo.y = cvtpk(l2, l3);
        *(uint2*)&s_xb[0][p * ROWS + c0] = hi;   // 8B-aligned: 272p + 8*(tid&31)
        *(uint2*)&s_xb[1][p * ROWS + c0] = lo;
    }
    __syncthreads();  // b5

    // E5: out = ctx @ wv (hi/lo split)
    f32x4 oA = {0.f, 0.f, 0.f, 0.f};
    #pragma unroll
    for (int kc = 0; kc < 4; ++kc) {
        bf16x8 bwh = *(const bf16x8*)&wpk[(((32 + kc) * 8 + w) * 64 + lane) * 8];
        bf16x8 bwl = *(const bf16x8*)&wpk[(((36 + kc) * 8 + w) * 64 + lane) * 8];
        bf16x8 Ah  = *(const bf16x8*)&s_xb[0][c16 * ROWS + kc * 32 + quad * 8];
        bf16x8 Al  = *(const bf16x8*)&s_xb[1][c16 * ROWS + kc * 32 + quad * 8];
        oA = MFMA(Ah, bwh, oA); oA = MFMA(Ah, bwl, oA); oA = MFMA(Al, bwh, oA);
    }
    #pragma unroll
    for (int r = 0; r < 4; ++r)
        out[(p0 + quad * 4 + r) * 128 + ucol] = oA[r];
}

extern "C" void kernel_launch(void* const* d_in, const int* in_sizes, int n_in,
                              void* d_out, int out_size, void* d_ws, size_t ws_size,
                              hipStream_t stream) {
    const float* inputs = (const float*)d_in[0];
    const int*   paths  = (const int*)d_in[1];
    // d_in[2]=idx, d_in[3]=seqs: layout known (p*16+s), unused
    const float* wx  = (const float*)d_in[4];
    const float* wr  = (const float*)d_in[5];
    const float* bi  = (const float*)d_in[6];
    const float* br  = (const float*)d_in[7];
    const float* wq  = (const float*)d_in[8];
    const float* wk  = (const float*)d_in[9];
    const float* wvp = (const float*)d_in[10];

    // workspace: E8 10,240,000 B | wpk 327,680 B  (total ~10.6 MB)
    char* ws = (char*)d_ws;
    uint2* E8 = (uint2*)ws;
    short* wpk = (short*)(ws + 10240000);

    int prep_n = GRU_T + QK_T + WV_T;
    prep_kernel<<<(prep_n + 255) / 256, 256, 0, stream>>>(wx, wr, wq, wk, wvp, wpk);
    eprep_kernel<<<NEDGES / 16, 512, 0, stream>>>(inputs, wpk, bi, E8);
    path_emb_kernel<<<NTILES, 512, 0, stream>>>(paths, wpk, E8, bi, br, (float*)d_out);
}